// Round 4
// baseline (144.645 us; speedup 1.0000x reference)
//
#include <hip/hip_runtime.h>
#include <stdint.h>

typedef unsigned long long u64;
typedef unsigned int u32;
typedef float f2 __attribute__((ext_vector_type(2)));

// ---- cross-lane helpers ----
__device__ __forceinline__ float dpp_shr1_f(float v, int fill_bits) {
  // within each 16-lane row: lane i <- lane i-1; row-lead keeps fill
  return __int_as_float(__builtin_amdgcn_update_dpp(
      fill_bits, __float_as_int(v), 0x111 /*row_shr:1*/, 0xF, 0xF, false));
}
__device__ __forceinline__ int dpp_shr1_i(int v) {
  return __builtin_amdgcn_update_dpp(0, v, 0x111, 0xF, 0xF, false);
}
// order-preserving float-bits -> u32 (monotone for all finite floats)
__device__ __forceinline__ u32 fkeyS(u32 s) {
  return s ^ ((u32)((int)s >> 31) | 0x80000000u);
}

// pack point pairs (n, n+32) of each 64-pt chunk:
// rec0 = {-2x0,-2x1,-2y0,-2y1}, rec1 = {-2z0,-2z1, pn0, pn1}
__global__ void prep_pack2(const float* __restrict__ pc, float4* __restrict__ pp,
                           int B, int N) {
  int r = blockIdx.x * blockDim.x + threadIdx.x;  // record id
  int H = N >> 1;
  if (r >= B * H) return;
  int b = r / H;
  int j = r - b * H;
  int k = j >> 5, t = j & 31;
  int n0 = (k << 6) + t, n1 = n0 + 32;
  const float* p = pc + (size_t)b * 3 * N;
  float x0 = p[n0], x1 = p[n1];
  float y0 = p[N + n0], y1 = p[N + n1];
  float z0 = p[2 * N + n0], z1 = p[2 * N + n1];
  float pn0 = __fadd_rn(__fadd_rn(__fmul_rn(x0, x0), __fmul_rn(y0, y0)),
                        __fmul_rn(z0, z0));
  float pn1 = __fadd_rn(__fadd_rn(__fmul_rn(x1, x1), __fmul_rn(y1, y1)),
                        __fmul_rn(z1, z1));
  pp[2 * r] = make_float4(__fmul_rn(x0, -2.0f), __fmul_rn(x1, -2.0f),
                          __fmul_rn(y0, -2.0f), __fmul_rn(y1, -2.0f));
  pp[2 * r + 1] = make_float4(__fmul_rn(z0, -2.0f), __fmul_rn(z1, -2.0f),
                              pn0, pn1);
}

template <bool PACKED>
__global__ __launch_bounds__(128, 8) void knn4(
    const float* __restrict__ pc,    // (B,3,N)
    const float* __restrict__ qc,    // (B,3,M)
    const float* __restrict__ temp,  // scalar
    const float4* __restrict__ pp,   // packed pair records
    float* __restrict__ out,         // (B,3,M)
    int B, int N, int M) {
#pragma clang fp contract(off)
  const float INF = __int_as_float(0x7f800000);
  const int NINF_BITS = (int)0xff800000;

  int tid = threadIdx.x;
  int lane = tid & 63;
  bool grpB = (lane >> 5) != 0;  // lanes 32-63 = query B of this wave
  bool ownA = !grpB;
  int sub = lane & 31;
  int qid = blockIdx.x * 4 + (tid >> 5);
  int b = qid >> 11;    // M = 2048
  int q = qid & 2047;

  float qx = qc[(b * 3 + 0) * M + q];
  float qy = qc[(b * 3 + 1) * M + q];
  float qz = qc[(b * 3 + 2) * M + q];
  float qn = __fadd_rn(__fadd_rn(__fmul_rn(qx, qx), __fmul_rn(qy, qy)),
                       __fmul_rn(qz, qz));
  f2 qx2 = {qx, qx}, qy2 = {qy, qy}, qz2 = {qz, qz}, qn2 = {qn, qn};

  // distributed top-16: lane (l&15) holds entry (l&15), ascending.
  // rows 0,1 mirror query A; rows 2,3 mirror query B.
  float val = INF;
  int idx = 0;
  float thresh = INF;

  const float* __restrict__ pcb = pc + (size_t)b * 3 * N;

  // sorted-insert of all candidates in mask m (bit k <-> point g+k, ascending)
  auto doInsert = [&](u64 m, f2 d2v, int g, int loff) {
    u32 thrKey = fkeyS((u32)__builtin_amdgcn_readlane(__float_as_int(val),
                                                      loff + 15));
    while (m) {
      int s = __ffsll(m) - 1;
      m &= m - 1;
      int cvb0 = __builtin_amdgcn_readlane(__float_as_int(d2v.x), loff + (s & 31));
      int cvb1 = __builtin_amdgcn_readlane(__float_as_int(d2v.y), loff + (s & 31));
      int cvb = (s < 32) ? cvb0 : cvb1;
      if (fkeyS((u32)cvb) >= thrKey) continue;  // scalar prune: no-op insert
      float cv = __int_as_float(cvb);
      int ci = g + s;
      float pvv = dpp_shr1_f(val, NINF_BITS);
      int piv = dpp_shr1_i(idx);
      bool own = (loff == 0) ? ownA : grpB;
      bool p = (cv < val) & own;   // strict < keeps top_k tie-break
      bool p2 = (cv < pvv);
      val = p ? (p2 ? pvv : cv) : val;
      idx = p ? (p2 ? piv : ci) : idx;
      thrKey = fkeyS((u32)__builtin_amdgcn_readlane(__float_as_int(val),
                                                    loff + 15));
    }
  };

  auto body = [&](float4 c0, float4 c1, int g) {
    f2 px = {c0.x, c0.y}, py = {c0.z, c0.w};
    f2 pz = {c1.x, c1.y}, pw = {c1.z, c1.w};
    // d2 = (qn+pn) + (qx*(-2px)+qy*(-2py)+qz*(-2pz))  == reference bit-exactly
    f2 s1 = qx2 * px;
    f2 s2 = qy2 * py;
    f2 s3 = qz2 * pz;
    f2 t = (s1 + s2) + s3;
    f2 u = qn2 + pw;
    f2 d2 = u + t;
    u64 m0 = __ballot(d2.x < thresh);
    u64 m1 = __ballot(d2.y < thresh);
    // per-query masks with bit k <-> point g+k
    u64 mA = (u64)(u32)m0 | ((u64)(u32)m1 << 32);
    u64 mB = (m0 >> 32) | ((m1 >> 32) << 32);
    if (mA) doInsert(mA, d2, g, 0);
    if (mB) doInsert(mB, d2, g, 32);
    if (mA | mB) {
      int tA = __builtin_amdgcn_readlane(__float_as_int(val), 15);
      int tB = __builtin_amdgcn_readlane(__float_as_int(val), 47);
      thresh = __int_as_float(grpB ? tB : tA);
    }
  };

  if (PACKED) {
    const int ITER = N >> 6;  // 128 iters of 64 points
    const float4* pbp = pp + ((size_t)b * (N >> 1) + sub) * 2;
    float4 c0 = pbp[0], c1 = pbp[1];
#pragma unroll 1
    for (int k = 0; k < ITER; ++k) {
      int kn = (k + 1 < ITER) ? (k + 1) : 0;
      float4 n0 = pbp[(size_t)kn * 64], n1 = pbp[(size_t)kn * 64 + 1];
      body(c0, c1, k << 6);
      c0 = n0; c1 = n1;
    }
  } else {
#pragma unroll 1
    for (int g = 0; g < N; g += 64) {
      int n0 = g + sub, n1 = g + sub + 32;
      float x0 = pcb[n0], x1 = pcb[n1];
      float y0 = pcb[N + n0], y1 = pcb[N + n1];
      float z0 = pcb[2 * N + n0], z1 = pcb[2 * N + n1];
      float pn0 = __fadd_rn(__fadd_rn(__fmul_rn(x0, x0), __fmul_rn(y0, y0)),
                            __fmul_rn(z0, z0));
      float pn1 = __fadd_rn(__fadd_rn(__fmul_rn(x1, x1), __fmul_rn(y1, y1)),
                            __fmul_rn(z1, z1));
      float4 c0 = make_float4(__fmul_rn(x0, -2.0f), __fmul_rn(x1, -2.0f),
                              __fmul_rn(y0, -2.0f), __fmul_rn(y1, -2.0f));
      float4 c1 = make_float4(__fmul_rn(z0, -2.0f), __fmul_rn(z1, -2.0f),
                              pn0, pn1);
      body(c0, c1, g);
    }
  }

  // ---- finisher: lane (l&15) owns entry (l&15); np-faithful arithmetic ----
  float Tv = temp[0];
  float sigma = fmaxf(__fmul_rn(Tv, Tv), 1e-4f);
  float sp = __fadd_rn(sigma, 1e-8f);
  int n = idx;
  float px = pcb[n], py = pcb[N + n], pz = pcb[2 * N + n];
  float dx = __fsub_rn(px, qx), dy = __fsub_rn(py, qy), dz = __fsub_rn(pz, qz);
  float d2w = __fadd_rn(__fadd_rn(__fmul_rn(dx, dx), __fmul_rn(dy, dy)),
                        __fmul_rn(dz, dz));
  float a = -__fdiv_rn(d2w, sp);  // -dist
  float m = __int_as_float(
      __builtin_amdgcn_readlane(__float_as_int(a), grpB ? 32 : 0));  // max
  float e = expf(__fsub_rn(a, m));
  float Z = e;
#pragma unroll
  for (int d = 1; d < 16; d <<= 1) Z += __shfl_xor(Z, d, 16);
  float w = __fdiv_rn(e, Z);  // normalized weight
  float sx = __fmul_rn(px, w), sy = __fmul_rn(py, w), sz = __fmul_rn(pz, w);
#pragma unroll
  for (int d = 1; d < 16; d <<= 1) {
    sx += __shfl_xor(sx, d, 16);
    sy += __shfl_xor(sy, d, 16);
    sz += __shfl_xor(sz, d, 16);
  }
  if ((lane & 31) < 3) {
    int c = lane & 31;
    float r = (c == 0) ? sx : ((c == 1) ? sy : sz);
    out[(b * 3 + c) * M + q] = r;
  }
}

extern "C" void kernel_launch(void* const* d_in, const int* in_sizes, int n_in,
                              void* d_out, int out_size, void* d_ws, size_t ws_size,
                              hipStream_t stream) {
  const int B = 8, N = 8192, M = 2048;
  const float* pc = (const float*)d_in[0];
  const float* qc = (const float*)d_in[1];
  const float* temp = (const float*)d_in[2];
  float* out = (float*)d_out;

  size_t packBytes = (size_t)B * N * 16;  // B*N/2 records * 32B
  bool packed = (ws_size >= packBytes) && (d_ws != nullptr);

  int nblocks = (B * M) / 4;  // 4 queries / 128-thread block (2 per wave)
  if (packed) {
    int R = B * (N >> 1);
    prep_pack2<<<dim3((R + 255) / 256), dim3(256), 0, stream>>>(
        pc, (float4*)d_ws, B, N);
    knn4<true><<<dim3(nblocks), dim3(128), 0, stream>>>(
        pc, qc, temp, (const float4*)d_ws, out, B, N, M);
  } else {
    knn4<false><<<dim3(nblocks), dim3(128), 0, stream>>>(
        pc, qc, temp, nullptr, out, B, N, M);
  }
}

// Round 5
// 112.079 us; speedup vs baseline: 1.2906x; 1.2906x over previous
//
#include <hip/hip_runtime.h>
#include <stdint.h>

typedef unsigned long long u64;
typedef unsigned int u32;
typedef float f2 __attribute__((ext_vector_type(2)));

// ---- cross-lane helpers ----
__device__ __forceinline__ float dpp_shr1_f(float v, int fill_bits) {
  // within each 16-lane row: lane i <- lane i-1; row-lead takes fill
  return __int_as_float(__builtin_amdgcn_update_dpp(
      fill_bits, __float_as_int(v), 0x111 /*row_shr:1*/, 0xF, 0xF, false));
}
__device__ __forceinline__ int dpp_shr1_i(int v) {
  return __builtin_amdgcn_update_dpp(0, v, 0x111, 0xF, 0xF, false);
}
__device__ __forceinline__ float rdlane_f(float v, int lane) {
  return __int_as_float(__builtin_amdgcn_readlane(__float_as_int(v), lane));
}

// pack point pairs (n, n+32) of each 64-pt chunk:
// rec0 = {-2x0,-2x1,-2y0,-2y1}, rec1 = {-2z0,-2z1, pn0, pn1}
__global__ void prep_pack2(const float* __restrict__ pc, float4* __restrict__ pp,
                           int B, int N) {
  int r = blockIdx.x * blockDim.x + threadIdx.x;  // record id
  int H = N >> 1;
  if (r >= B * H) return;
  int b = r / H;
  int j = r - b * H;
  int k = j >> 5, t = j & 31;
  int n0 = (k << 6) + t, n1 = n0 + 32;
  const float* p = pc + (size_t)b * 3 * N;
  float x0 = p[n0], x1 = p[n1];
  float y0 = p[N + n0], y1 = p[N + n1];
  float z0 = p[2 * N + n0], z1 = p[2 * N + n1];
  float pn0 = __fadd_rn(__fadd_rn(__fmul_rn(x0, x0), __fmul_rn(y0, y0)),
                        __fmul_rn(z0, z0));
  float pn1 = __fadd_rn(__fadd_rn(__fmul_rn(x1, x1), __fmul_rn(y1, y1)),
                        __fmul_rn(z1, z1));
  pp[2 * r] = make_float4(__fmul_rn(x0, -2.0f), __fmul_rn(x1, -2.0f),
                          __fmul_rn(y0, -2.0f), __fmul_rn(y1, -2.0f));
  pp[2 * r + 1] = make_float4(__fmul_rn(z0, -2.0f), __fmul_rn(z1, -2.0f),
                              pn0, pn1);
}

template <bool PACKED>
__global__ __launch_bounds__(256, 8) void knn5(
    const float* __restrict__ pc,    // (B,3,N)
    const float* __restrict__ qc,    // (B,3,M)
    const float* __restrict__ temp,  // scalar
    const float4* __restrict__ pp,   // packed pair records
    float* __restrict__ out,         // (B,3,M)
    int B, int N, int M) {
#pragma clang fp contract(off)
  const float INF = __int_as_float(0x7f800000);
  const int NINF_BITS = (int)0xff800000;

  int tid = threadIdx.x;
  int lane = tid & 63;
  int grp = lane >> 5;   // 0: lanes 0-31 = query A; 1: lanes 32-63 = query B
  int sub = lane & 31;
  int qid = blockIdx.x * 8 + (tid >> 5);
  int b = qid >> 11;     // M = 2048
  int q = qid & 2047;

  float qx = qc[(b * 3 + 0) * M + q];
  float qy = qc[(b * 3 + 1) * M + q];
  float qz = qc[(b * 3 + 2) * M + q];
  float qn = __fadd_rn(__fadd_rn(__fmul_rn(qx, qx), __fmul_rn(qy, qy)),
                       __fmul_rn(qz, qz));
  f2 qx2 = {qx, qx}, qy2 = {qy, qy}, qz2 = {qz, qz}, qn2 = {qn, qn};

  // distributed top-16: lane (l&15) holds entry (l&15), ascending.
  // rows 0,1 mirror query A; rows 2,3 mirror query B.
  float val = INF;
  int idx = 0;
  float thresh = INF;
  int bperm_addr = ((lane < 32) ? 15 : 47) << 2;  // own group's entry 15

  const float* __restrict__ pcb = pc + (size_t)b * 3 * N;

  // merged A/B sorted-insert: one candidate from each query per round
  // (R3 structure: branchless, no per-round scalar threshold chain)
  auto insert32 = [&](u32 mA, u32 mB, float dv, int g) {
    while (mA | mB) {
      int sA = __ffs(mA) - 1;     // ascending index = top_k tie-break
      int sB = __ffs(mB) - 1;
      int lA = (sA < 0) ? 0 : sA;
      int lB = (sB < 0) ? 32 : (sB + 32);
      float cA = rdlane_f(dv, lA);
      float cB = rdlane_f(dv, lB);
      if (sA < 0) cA = INF;
      if (sB < 0) cB = INF;
      int ciA = g + lA;
      int ciB = g + (lB - 32);
      float cv = grp ? cB : cA;
      int ci = grp ? ciB : ciA;
      float pvv = dpp_shr1_f(val, NINF_BITS);
      int piv = dpp_shr1_i(idx);
      bool p = cv < val;          // strict < keeps stability
      bool p2 = cv < pvv;
      val = p ? (p2 ? pvv : cv) : val;
      idx = p ? (p2 ? piv : ci) : idx;
      if (mA) mA &= mA - 1;
      if (mB) mB &= mB - 1;
    }
  };

  auto body = [&](float4 c0, float4 c1, int g) {
    f2 px = {c0.x, c0.y}, py = {c0.z, c0.w};
    f2 pz = {c1.x, c1.y}, pw = {c1.z, c1.w};
    // d2 = (qn+pn) + (qx*(-2px)+qy*(-2py)+qz*(-2pz))  == reference bit-exactly
    f2 s1 = qx2 * px;
    f2 s2 = qy2 * py;
    f2 s3 = qz2 * pz;
    f2 t = (s1 + s2) + s3;
    f2 d2 = (qn2 + pw) + t;
    u64 m0 = __ballot(d2.x < thresh);  // points g   .. g+31
    u64 m1 = __ballot(d2.y < thresh);  // points g+32.. g+63
    if (m0 | m1) {
      if (m0) insert32((u32)m0, (u32)(m0 >> 32), d2.x, g);
      if (m1) insert32((u32)m1, (u32)(m1 >> 32), d2.y, g + 32);
      // refresh own group's threshold = entry 15 (LDS pipe, off VALU)
      thresh = __int_as_float(
          __builtin_amdgcn_ds_bpermute(bperm_addr, __float_as_int(val)));
    }
  };

  if (PACKED) {
    const int ITER = N >> 6;  // 128 chunks of 64 points
    const float4* __restrict__ pbp = pp + ((size_t)b * (N >> 1) + sub) * 2;
    float4 a0 = pbp[0], a1 = pbp[1];
#pragma unroll 1
    for (int it = 0; it < ITER; it += 2) {
      size_t o1 = (size_t)(it + 1) * 64;
      float4 b0 = pbp[o1], b1 = pbp[o1 + 1];
      body(a0, a1, it << 6);
      size_t o2 = (size_t)((it + 2) & (ITER - 1)) * 64;  // wrap harmless
      a0 = pbp[o2]; a1 = pbp[o2 + 1];
      body(b0, b1, (it + 1) << 6);
    }
  } else {
#pragma unroll 1
    for (int g = 0; g < N; g += 64) {
      int n0 = g + sub, n1 = g + sub + 32;
      float x0 = pcb[n0], x1 = pcb[n1];
      float y0 = pcb[N + n0], y1 = pcb[N + n1];
      float z0 = pcb[2 * N + n0], z1 = pcb[2 * N + n1];
      float pn0 = __fadd_rn(__fadd_rn(__fmul_rn(x0, x0), __fmul_rn(y0, y0)),
                            __fmul_rn(z0, z0));
      float pn1 = __fadd_rn(__fadd_rn(__fmul_rn(x1, x1), __fmul_rn(y1, y1)),
                            __fmul_rn(z1, z1));
      float4 c0 = make_float4(__fmul_rn(x0, -2.0f), __fmul_rn(x1, -2.0f),
                              __fmul_rn(y0, -2.0f), __fmul_rn(y1, -2.0f));
      float4 c1 = make_float4(__fmul_rn(z0, -2.0f), __fmul_rn(z1, -2.0f),
                              pn0, pn1);
      body(c0, c1, g);
    }
  }

  // ---- finisher (R3 verbatim, np-faithful): lane (l&15) owns entry (l&15) ----
  float Tv = temp[0];
  float sigma = fmaxf(__fmul_rn(Tv, Tv), 1e-4f);
  float sp = __fadd_rn(sigma, 1e-8f);
  int n = idx;
  float px = pcb[n], py = pcb[N + n], pz = pcb[2 * N + n];
  float dx = __fsub_rn(px, qx), dy = __fsub_rn(py, qy), dz = __fsub_rn(pz, qz);
  float d2w = __fadd_rn(__fadd_rn(__fmul_rn(dx, dx), __fmul_rn(dy, dy)),
                        __fmul_rn(dz, dz));
  float a = -__fdiv_rn(d2w, sp);                     // -dist
  float m = grp ? rdlane_f(a, 32) : rdlane_f(a, 0);  // max = entry 0 (sorted)
  float e = expf(__fsub_rn(a, m));
  float Z = e;
#pragma unroll
  for (int d = 1; d < 16; d <<= 1) Z += __shfl_xor(Z, d, 16);
  float w = __fdiv_rn(e, Z);                         // normalized weight
  float sx = __fmul_rn(px, w), sy = __fmul_rn(py, w), sz = __fmul_rn(pz, w);
#pragma unroll
  for (int d = 1; d < 16; d <<= 1) {
    sx += __shfl_xor(sx, d, 16);
    sy += __shfl_xor(sy, d, 16);
    sz += __shfl_xor(sz, d, 16);
  }
  if ((lane & 31) < 3) {
    int c = lane & 31;
    float r = (c == 0) ? sx : ((c == 1) ? sy : sz);
    out[(b * 3 + c) * M + q] = r;
  }
}

extern "C" void kernel_launch(void* const* d_in, const int* in_sizes, int n_in,
                              void* d_out, int out_size, void* d_ws, size_t ws_size,
                              hipStream_t stream) {
  const int B = 8, N = 8192, M = 2048;
  const float* pc = (const float*)d_in[0];
  const float* qc = (const float*)d_in[1];
  const float* temp = (const float*)d_in[2];
  float* out = (float*)d_out;

  size_t packBytes = (size_t)B * N * 16;  // B*N/2 records * 32B
  bool packed = (ws_size >= packBytes) && (d_ws != nullptr);

  int nblocks = (B * M) / 8;  // 8 queries / 256-thread block (2 per wave)
  if (packed) {
    int R = B * (N >> 1);
    prep_pack2<<<dim3((R + 255) / 256), dim3(256), 0, stream>>>(
        pc, (float4*)d_ws, B, N);
    knn5<true><<<dim3(nblocks), dim3(256), 0, stream>>>(
        pc, qc, temp, (const float4*)d_ws, out, B, N, M);
  } else {
    knn5<false><<<dim3(nblocks), dim3(256), 0, stream>>>(
        pc, qc, temp, nullptr, out, B, N, M);
  }
}